// Round 2
// baseline (1033.147 us; speedup 1.0000x reference)
//
#include <hip/hip_runtime.h>
#include <math.h>
#include <float.h>

#define NTOK  16384
#define DDIM  2048
#define TOPK  8
#define GR    16
#define ROWS  64          // rows per block (lane = row)
#define KB    64          // k-chunk
#define XST   68          // x-tile row stride: (17*lane)%8 uniform -> conflict-free b128
#define SST   148         // S spill stride (mult of 4 for aligned float4 reads)
#define CPW   18          // cols per wave (8 waves * 18 = 144)

// Insert (nv,nk) into descending top-8; ties -> smaller index first (lax.top_k stable).
__device__ __forceinline__ void insert8(float v[TOPK], int id[TOPK], float nv, int nk)
{
    bool beats_last = (nv > v[TOPK-1]) || (nv == v[TOPK-1] && nk < id[TOPK-1]);
    if (!beats_last) return;
    v[TOPK-1] = nv; id[TOPK-1] = nk;
    #pragma unroll
    for (int q = TOPK-1; q > 0; --q) {
        bool sw = (v[q] > v[q-1]) || (v[q] == v[q-1] && id[q] < id[q-1]);
        if (sw) {
            float tv = v[q]; v[q] = v[q-1]; v[q-1] = tv;
            int   ti = id[q]; id[q] = id[q-1]; id[q-1] = ti;
        }
    }
}

__global__ __launch_bounds__(512, 2) void pk_router(
    const float* __restrict__ x,  const float* __restrict__ W1,
    const float* __restrict__ W2, const float* __restrict__ Wg,
    const float* __restrict__ G,  float* __restrict__ out)
{
    // Union: during GEMM first 2*ROWS*XST = 8704 floats hold the x double-buffer;
    // after the k-loop the whole region becomes the S spill [64][148].
    __shared__ float lds[ROWS * SST];              // 9472 floats = 37888 B
    float* xs0 = lds;
    float* xs1 = lds + ROWS * XST;

    const int t    = threadIdx.x;
    const int rb   = blockIdx.x * ROWS;
    const int wid  = __builtin_amdgcn_readfirstlane(t >> 6);   // wave id 0..7 (uniform)
    const int lane = t & 63;                                    // = row within tile

    // Per-wave W column base pointers — fully uniform => SGPRs => s_load path.
    const float* wp[CPW];
    #pragma unroll
    for (int c = 0; c < CPW; ++c) {
        const int gc = wid * CPW + c;   // global col 0..143
        wp[c] = (gc < 64)  ? (W1 + (size_t)gc * DDIM)
              : (gc < 128) ? (W2 + (size_t)(gc - 64) * DDIM)
                           : (Wg + (size_t)(gc - 128) * DDIM);
    }

    float acc[CPW];
    #pragma unroll
    for (int c = 0; c < CPW; ++c) acc[c] = 0.f;

    // Staging map: 1024 float4 per chunk = 64 rows x 16 f4; thread does f4 #t and #(t+512).
    const int sr0 = t >> 4;             // row 0..31
    const int sr1 = sr0 + 32;           // row 32..63
    const int sk0 = (t & 15) * 4;       // k offset within chunk
    const float* gx0 = x + (size_t)(rb + sr0) * DDIM + sk0;
    const float* gx1 = x + (size_t)(rb + sr1) * DDIM + sk0;

    // prime chunk 0
    {
        const float4 p0 = *(const float4*)(gx0);
        const float4 p1 = *(const float4*)(gx1);
        *(float4*)(xs0 + sr0 * XST + sk0) = p0;   // ds_write_b128, conflict-free
        *(float4*)(xs0 + sr1 * XST + sk0) = p1;
    }
    __syncthreads();

    for (int kb = 0; kb < DDIM; kb += KB) {
        float* xb = (kb & KB) ? xs1 : xs0;
        float4 n0, n1;
        const bool more = (kb + KB) < DDIM;
        if (more) {                                  // prefetch next chunk into regs
            n0 = *(const float4*)(gx0 + kb + KB);
            n1 = *(const float4*)(gx1 + kb + KB);
        }
        const float* xr = xb + lane * XST;
        #pragma unroll 2
        for (int kk = 0; kk < KB; kk += 4) {
            const float4 a = *(const float4*)(xr + kk);          // 1 ds_read_b128
            #pragma unroll
            for (int c = 0; c < CPW; ++c) {
                const float4 w = *(const float4*)(wp[c] + kb + kk);  // uniform -> s_load_dwordx4
                // strictly sequential k-order: bitwise-identical to the R1 pass
                acc[c] += a.x * w.x;
                acc[c] += a.y * w.y;
                acc[c] += a.z * w.z;
                acc[c] += a.w * w.w;
            }
        }
        __syncthreads();
        if (more) {
            float* xn = ((kb + KB) & KB) ? xs1 : xs0;
            *(float4*)(xn + sr0 * XST + sk0) = n0;
            *(float4*)(xn + sr1 * XST + sk0) = n1;
            __syncthreads();
        }
    }

    // ---- spill S[64][144] (aliases x buffers; safe after final barrier)
    #pragma unroll
    for (int c = 0; c < CPW; ++c)
        lds[lane * SST + wid * CPW + c] = acc[c];
    __syncthreads();

    // ---- phase 3a: scores[rb..rb+63][0..4095], coalesced float4
    // out layout: [idx NTOK*8][weights NTOK*8][scores NTOK*4096]
    const size_t scoreBase = (size_t)NTOK * 2 * TOPK + (size_t)rb * 4096;
    const int i0 = t >> 4;              // 0..31
    const int j4 = (t & 15) * 4;
    for (int r = 0; r < ROWS; ++r) {
        const float* Sr = lds + r * SST;
        const float4 s2v = *(const float4*)(Sr + 64 + j4);
        const float s1a = Sr[i0];
        const float s1b = Sr[i0 + 32];
        float4 oa, ob;
        oa.x = s1a + s2v.x; oa.y = s1a + s2v.y; oa.z = s1a + s2v.z; oa.w = s1a + s2v.w;
        ob.x = s1b + s2v.x; ob.y = s1b + s2v.y; ob.z = s1b + s2v.z; ob.w = s1b + s2v.w;
        float* od = out + scoreBase + (size_t)r * 4096;
        *(float4*)(od + (size_t)(i0 * 64 + j4))        = oa;
        *(float4*)(od + (size_t)((i0 + 32) * 64 + j4)) = ob;
    }

    // ---- phase 3b: per-row top-8 + gate + softmax; full wave 0 (64 lanes = 64 rows)
    if (t < ROWS) {
        const float* Srow = lds + t * SST;
        float v1[TOPK], v2[TOPK]; int i1[TOPK], i2[TOPK];
        #pragma unroll
        for (int e = 0; e < TOPK; ++e) { v1[e] = -FLT_MAX; v2[e] = -FLT_MAX; i1[e] = 1<<30; i2[e] = 1<<30; }
        for (int i = 0; i < 64; ++i) insert8(v1, i1, Srow[i], i);
        for (int j = 0; j < 64; ++j) insert8(v2, i2, Srow[64 + j], j);

        // true top-8 of s1[i]+s2[j] ⊆ top8(s1) x top8(s2) under (val desc, idx asc)
        float cv[TOPK]; int ck[TOPK];
        #pragma unroll
        for (int e = 0; e < TOPK; ++e) { cv[e] = -FLT_MAX; ck[e] = 1<<30; }
        #pragma unroll
        for (int a = 0; a < TOPK; ++a) {
            #pragma unroll
            for (int b = 0; b < TOPK; ++b)
                insert8(cv, ck, v1[a] + v2[b], i1[a]*64 + i2[b]);
        }

        float qg[GR];
        #pragma unroll
        for (int u = 0; u < GR; ++u) qg[u] = Srow[128 + u];

        float comb[TOPK];
        #pragma unroll
        for (int e = 0; e < TOPK; ++e) {
            const float* gp = G + (size_t)ck[e] * GR;
            float dot = 0.f;
            #pragma unroll
            for (int u = 0; u < GR; ++u) dot += qg[u] * gp[u];
            comb[e] = cv[e] + dot;
        }
        float m = comb[0];
        #pragma unroll
        for (int e = 1; e < TOPK; ++e) m = fmaxf(m, comb[e]);
        float w[TOPK]; float s = 0.f;
        #pragma unroll
        for (int e = 0; e < TOPK; ++e) { w[e] = expf(comb[e] - m); s += w[e]; }
        const float inv = 1.f / s;

        const size_t row = (size_t)rb + t;
        #pragma unroll
        for (int e = 0; e < TOPK; ++e) {
            out[row * TOPK + e] = (float)ck[e];                        // indices as float
            out[(size_t)NTOK * TOPK + row * TOPK + e] = w[e] * inv;    // weights
        }
    }
}

extern "C" void kernel_launch(void* const* d_in, const int* in_sizes, int n_in,
                              void* d_out, int out_size, void* d_ws, size_t ws_size,
                              hipStream_t stream)
{
    const float* x  = (const float*)d_in[0];
    const float* W1 = (const float*)d_in[1];
    const float* W2 = (const float*)d_in[2];
    const float* Wg = (const float*)d_in[3];
    const float* G  = (const float*)d_in[4];
    float* out = (float*)d_out;

    pk_router<<<dim3(NTOK / ROWS), dim3(512), 0, stream>>>(x, W1, W2, Wg, G, out);
}